// Round 6
// baseline (13421.915 us; speedup 1.0000x reference)
//
#include <hip/hip_runtime.h>
#include <math.h>

// GRU enc-dec w/ attention. B=32,S=512,T=128,V=128,L=5,E=512,H=1024,F=2048.
// R8: persistent decoder (mirrors R7's validated persistent encoder).
//     ONE cooperative kernel, 256 blk x 256 thr (1 blk/CU, ~127KB LDS).
//     Roles: blk 0-63 gh (Whd 16-col slice in LDS), 64-127 gi (Wic slice),
//     128-255 attention (2 scores/thread, exact k_rec order) + hc-fold;
//     all blocks run ctxsm phase (exact k_ctxsm body). 3 custom barriers/step
//     (release atomicAdd + poll + acquire) replace 3 launches. Init folded in.

#define Bb 32
#define Ss 512
#define Tt 128
#define Vv 128
#define Hh 1024
#define H3 3072
#define APAD 40
#define NBE 64    // persistent encoder blocks
#define NBD 256   // persistent decoder blocks

typedef __attribute__((ext_vector_type(8))) short bf16x8;
typedef __attribute__((ext_vector_type(4))) float f32x4;

__device__ inline f32x4 mfma_bf16(bf16x8 a, bf16x8 b, f32x4 c) {
  return __builtin_amdgcn_mfma_f32_16x16x32_bf16(a, b, c, 0, 0, 0);
}
__device__ inline unsigned short f2bf(float f) {
  unsigned u = __builtin_bit_cast(unsigned, f);
  unsigned r = (u + 0x7fffu + ((u >> 16) & 1u)) >> 16;
  return (unsigned short)r;
}
__device__ inline float lof(unsigned u) { return __builtin_bit_cast(float, u << 16); }
__device__ inline float hif(unsigned u) { return __builtin_bit_cast(float, u & 0xffff0000u); }
__device__ inline float bf2f(unsigned short h) {
  return __builtin_bit_cast(float, ((unsigned)h) << 16);
}

// global barrier: all threads sync, tid0 release-adds (flushes dirty L2),
// polls, acquire-fences (invalidates L1/L2). Validated in R7's encoder.
__device__ inline void gbar(int* bar, int nb, int& bc) {
  __syncthreads();
  if (threadIdx.x == 0) {
    __hip_atomic_fetch_add(bar, 1, __ATOMIC_RELEASE, __HIP_MEMORY_SCOPE_AGENT);
    ++bc;
    int tgt = nb * bc;
    while (__hip_atomic_load(bar, __ATOMIC_RELAXED, __HIP_MEMORY_SCOPE_AGENT) < tgt)
      __builtin_amdgcn_s_sleep(1);
    __builtin_amdgcn_fence(__ATOMIC_ACQUIRE, "agent");
  }
  __syncthreads();
}

// ---------------- workspace offsets (BYTES) ----------------
#define O_ESBF   0UL            // es bf16      [B*S][1024]  32MB
#define O_ESQ    33554432UL     // esq bf16     [B*S][1024]  32MB  (aliased: G1 in MLP)
#define O_AVBF   67108864UL     // av bf16      [B*S][1024]  32MB  (aliased: G2 in MLP)
#define O_HCBF   100663296UL    // hc bf16      [T*B][1024]   8MB
#define O_WHE    109051904UL    // enc_Wh bf16  [3072][1024]  6MB
#define O_WHD    115343360UL    // dec_Wh bf16  6MB
#define O_WIC    121634816UL    // dec_Wi ctx-cols bf16 [3072][1024] 6MB
#define O_WKB    127926272UL    // Wk bf16 [1024][1024] 2MB
#define O_WQT    130023424UL    // Wq^T bf16 [1024][1024] 2MB
#define O_W1B    132120576UL    // W1 bf16 [4096][1024] 8MB
#define O_W2B    140509184UL    // W2 bf16 [2048][4096] 16MB
#define O_W3B    157286400UL    // W3 bf16 [128][2048] 0.5MB
#define O_XCAT   157810688UL    // fp32 [640][1024]
#define O_EMBFC  160432128UL    // fp32 [640][512]
#define O_GITAB  161742848UL    // fp32 [640][3072]
#define O_AVTAB  169607168UL    // fp32 [640][1024]
#define O_DGIXT  172228608UL    // fp32 [128][3072]
#define O_GH     173801472UL    // fp32 [32][3072]
#define O_GI     174194688UL    // 384KB: cltab(64KB) + hbf2(64KB) + bars
#define O_H      174587904UL    // fp32 [32][1024]
#define O_HBF    174718976UL    // bf16 [32][1024]
#define O_CTX    174784512UL    // fp32 [32][1024]
#define O_CTXBF  174915584UL    // bf16 [32][1024]
#define O_ATTL   174981120UL    // fp32 [32][512]
// total ~167MB

// ---------------- setup helpers ----------------
__global__ void k_xcat(const float* __restrict__ ce, const float* __restrict__ le,
                       float* __restrict__ xcat) {
  int row = blockIdx.x;  // l*128 + c
  int l = row >> 7, c = row & 127;
  int i = threadIdx.x * 4;
  float4 v;
  if (i < 512) v = *(const float4*)(ce + c * 512 + i);
  else         v = *(const float4*)(le + l * 512 + (i - 512));
  *(float4*)(xcat + (size_t)row * 1024 + i) = v;
}

__global__ void k_cltab(const int* __restrict__ sc, const int* __restrict__ sl,
                        int* __restrict__ cl, int* __restrict__ bar) {
  if (blockIdx.x == 0 && threadIdx.x == 0) { bar[0] = 0; bar[32] = 0; }
  int i = blockIdx.x * 256 + threadIdx.x;  // 16384 = 32b * 512s
  int b = i >> 9, s = i & 511;
  cl[s * 32 + b] = sl[b * Ss + s] * 128 + sc[b * Ss + s];
}

__global__ void k_cvt(const float* __restrict__ src, int ld, int lc,
                      unsigned short* __restrict__ dst) {
  size_t i = ((size_t)blockIdx.x * 256 + threadIdx.x) * 8;
  size_t r = i >> lc;
  int c = (int)(i & ((1u << lc) - 1));
  const float* s = src + r * (size_t)ld + c;
  float4 v0 = *(const float4*)s;
  float4 v1 = *(const float4*)(s + 4);
  union { unsigned short us[8]; uint4 u; } o;
  o.us[0] = f2bf(v0.x); o.us[1] = f2bf(v0.y); o.us[2] = f2bf(v0.z); o.us[3] = f2bf(v0.w);
  o.us[4] = f2bf(v1.x); o.us[5] = f2bf(v1.y); o.us[6] = f2bf(v1.z); o.us[7] = f2bf(v1.w);
  *(uint4*)(dst + i) = o.u;
}

__global__ void k_transcvt(const float* __restrict__ in, unsigned short* __restrict__ out) {
  __shared__ float t[32][33];
  int c0 = blockIdx.x * 32, r0 = blockIdx.y * 32;
  int tx = threadIdx.x, ty = threadIdx.y;
  for (int i = ty; i < 32; i += 8)
    t[i][tx] = in[(size_t)(r0 + i) * 1024 + c0 + tx];
  __syncthreads();
  for (int i = ty; i < 32; i += 8)
    out[(size_t)(c0 + i) * 1024 + r0 + tx] = f2bf(t[tx][i]);
}

// ---------------- fp32 tiled GEMM (setup tables only): C=A@W^T ----------------
template <bool BIAS>
__global__ __launch_bounds__(256) void k_gemm(
    const float* __restrict__ A, int lda, const float* __restrict__ W, int ldw,
    const float* __restrict__ bias, float* __restrict__ C, int ldc, int K) {
  __shared__ float As[8][128];
  __shared__ float Ws[8][128];
  int tid = threadIdx.x;
  int n0 = blockIdx.x * 128, m0 = blockIdx.y * 128;
  int tx = tid & 15, ty = tid >> 4;
  int lrow = tid >> 1, lseg = (tid & 1) * 4;
  const float* Ap = A + (size_t)(m0 + lrow) * lda + lseg;
  const float* Wp = W + (size_t)(n0 + lrow) * ldw + lseg;
  float acc[8][8];
#pragma unroll
  for (int i = 0; i < 8; ++i)
#pragma unroll
    for (int j = 0; j < 8; ++j) acc[i][j] = 0.f;
  for (int kt = 0; kt < K; kt += 8) {
    float4 av = *(const float4*)(Ap + kt);
    float4 wv = *(const float4*)(Wp + kt);
    __syncthreads();
    As[lseg + 0][lrow] = av.x; As[lseg + 1][lrow] = av.y;
    As[lseg + 2][lrow] = av.z; As[lseg + 3][lrow] = av.w;
    Ws[lseg + 0][lrow] = wv.x; Ws[lseg + 1][lrow] = wv.y;
    Ws[lseg + 2][lrow] = wv.z; Ws[lseg + 3][lrow] = wv.w;
    __syncthreads();
#pragma unroll
    for (int kk = 0; kk < 8; ++kk) {
      float a[8], b[8];
      *(float4*)(a + 0) = *(const float4*)(&As[kk][ty * 8 + 0]);
      *(float4*)(a + 4) = *(const float4*)(&As[kk][ty * 8 + 4]);
      *(float4*)(b + 0) = *(const float4*)(&Ws[kk][tx * 8 + 0]);
      *(float4*)(b + 4) = *(const float4*)(&Ws[kk][tx * 8 + 4]);
#pragma unroll
      for (int i = 0; i < 8; ++i)
#pragma unroll
        for (int j = 0; j < 8; ++j) acc[i][j] = fmaf(a[i], b[j], acc[i][j]);
    }
  }
#pragma unroll
  for (int i = 0; i < 8; ++i) {
    int r = m0 + ty * 8 + i;
#pragma unroll
    for (int j = 0; j < 8; ++j) {
      int c = n0 + tx * 8 + j;
      float v = acc[i][j];
      if (BIAS) v += bias[c];
      C[(size_t)r * ldc + c] = v;
    }
  }
}

// ---------------- bf16 MFMA GEMM: C[M,N] = A[M,K] @ W[N,K]^T ----------------
// EPI: 0 store bf16; 1 +=avtab[lang*128+char][col], store bf16; 2 fp32 scatter to out
template <int EPI, bool RELU, bool BIAS>
__global__ __launch_bounds__(256) void k_bgemm(
    const unsigned short* __restrict__ A, int lda,
    const unsigned short* __restrict__ W, int ldw,
    const float* __restrict__ bias, void* __restrict__ Cout, int ldc, int K,
    const float* __restrict__ avtab, const int* __restrict__ gl,
    const int* __restrict__ gc) {
  __shared__ unsigned short As[128 * APAD];
  __shared__ unsigned short Bs[128 * APAD];
  int tid = threadIdx.x;
  int n0 = blockIdx.x * 128, m0 = blockIdx.y * 128;
  int w = tid >> 6, l = tid & 63;
  int mw = (w & 1) * 64, nw = (w >> 1) * 64;
  int lrow = tid >> 1, lk = (tid & 1) * 16;
  const unsigned short* Ap = A + (size_t)(m0 + lrow) * lda + lk;
  const unsigned short* Wp = W + (size_t)(n0 + lrow) * ldw + lk;
  int fr = l & 15, fk = (l >> 4) * 8;
  f32x4 acc[4][4];
#pragma unroll
  for (int i = 0; i < 4; ++i)
#pragma unroll
    for (int j = 0; j < 4; ++j) acc[i][j] = (f32x4){0.f, 0.f, 0.f, 0.f};
  for (int kt = 0; kt < K; kt += 32) {
    uint4 a0 = *(const uint4*)(Ap + kt);
    uint4 a1 = *(const uint4*)(Ap + kt + 8);
    uint4 b0 = *(const uint4*)(Wp + kt);
    uint4 b1 = *(const uint4*)(Wp + kt + 8);
    __syncthreads();
    *(uint4*)&As[lrow * APAD + lk] = a0;
    *(uint4*)&As[lrow * APAD + lk + 8] = a1;
    *(uint4*)&Bs[lrow * APAD + lk] = b0;
    *(uint4*)&Bs[lrow * APAD + lk + 8] = b1;
    __syncthreads();
    bf16x8 af[4], bfg[4];
#pragma unroll
    for (int i = 0; i < 4; ++i) af[i] = *(const bf16x8*)&As[(mw + i * 16 + fr) * APAD + fk];
#pragma unroll
    for (int j = 0; j < 4; ++j) bfg[j] = *(const bf16x8*)&Bs[(nw + j * 16 + fr) * APAD + fk];
#pragma unroll
    for (int i = 0; i < 4; ++i)
#pragma unroll
      for (int j = 0; j < 4; ++j) acc[i][j] = mfma_bf16(af[i], bfg[j], acc[i][j]);
  }
#pragma unroll
  for (int i = 0; i < 4; ++i)
#pragma unroll
    for (int j = 0; j < 4; ++j) {
      int col = n0 + nw + j * 16 + fr;
#pragma unroll
      for (int r = 0; r < 4; ++r) {
        int row = m0 + mw + i * 16 + (l >> 4) * 4 + r;
        float v = acc[i][j][r];
        if (BIAS) v += bias[col];
        if (RELU) v = fmaxf(v, 0.f);
        if (EPI == 0) {
          ((unsigned short*)Cout)[(size_t)row * ldc + col] = f2bf(v);
        } else if (EPI == 1) {
          int cl = gl[row] * 128 + gc[row];
          ((unsigned short*)Cout)[(size_t)row * ldc + col] =
              f2bf(v + avtab[(size_t)cl * 1024 + col]);
        } else {
          int tt = row >> 5, bb = row & 31;
          ((float*)Cout)[(size_t)bb * (Tt * Vv) + tt * Vv + col] = v;
        }
      }
    }
}

// ---------------- persistent encoder scan (unchanged from R7) ----------------
__global__ __launch_bounds__(512) void k_enc_pers(
    const unsigned short* __restrict__ Whe, const float* __restrict__ gitab,
    const int* __restrict__ cltab, const float* __restrict__ bh,
    float* __restrict__ h, unsigned short* __restrict__ hbf0,
    unsigned short* __restrict__ hbf1, unsigned short* __restrict__ esb,
    int* __restrict__ bar) {
  __shared__ unsigned short Ws[48 * 1024];  // 96KB
  __shared__ f32x4 red[8 * 6 * 64];         // 48KB
  int tid = threadIdx.x;
  int blk = blockIdx.x;
  int w = tid >> 6, l = tid & 63;
  int fr = l & 15, q = l >> 4;
  int j = blk * 16 + fr;
  {  // stage 48 Wh rows, XOR-swizzled per 16B chunk
    uint4* dst = (uint4*)Ws;
    const uint4* src = (const uint4*)Whe;
#pragma unroll
    for (int it = 0; it < 12; ++it) {
      int idx = it * 512 + tid;           // 0..6143
      int lr = idx >> 7, c = idx & 127;   // local row, chunk
      int grow = (lr >> 4) * 1024 + blk * 16 + (lr & 15);
      dst[lr * 128 + (c ^ (lr & 7))] = src[(size_t)grow * 128 + c];
    }
  }
  float bhr = bh[j], bhz = bh[1024 + j], bhn = bh[2048 + j];
  float hold[4] = {0.f, 0.f, 0.f, 0.f};
  __syncthreads();
  const bf16x8* Wsv = (const bf16x8*)Ws;
  int bc = 0;
  for (int s = 0; s < Ss; ++s) {
    unsigned short* wb = (s & 1) ? hbf1 : hbf0;
    const unsigned short* rb = (s & 1) ? hbf0 : hbf1;
    float gi0[4], gi1[4], gi2[4];
    if (w < 2) {
#pragma unroll
      for (int r = 0; r < 4; ++r) {
        int b = w * 16 + q * 4 + r;
        int c = cltab[s * 32 + b];
        const float* gp = gitab + (size_t)c * H3 + j;
        gi0[r] = gp[0]; gi1[r] = gp[1024]; gi2[r] = gp[2048];
      }
    }
    f32x4 acc[2][3];
#pragma unroll
    for (int m = 0; m < 2; ++m)
#pragma unroll
      for (int g = 0; g < 3; ++g) acc[m][g] = (f32x4){0.f, 0.f, 0.f, 0.f};
    if (s > 0) {
      int kb = w * 128 + q * 8;
      const unsigned short* A0 = rb + fr * 1024 + kb;
#pragma unroll
      for (int kt = 0; kt < 128; kt += 32) {
        bf16x8 a0 = *(const bf16x8*)(A0 + kt);
        bf16x8 a1 = *(const bf16x8*)(A0 + 16 * 1024 + kt);
        int c8 = (kb + kt) >> 3;
#pragma unroll
        for (int g = 0; g < 3; ++g) {
          bf16x8 bw = Wsv[(g * 16 + fr) * 128 + (c8 ^ (fr & 7))];
          acc[0][g] = mfma_bf16(a0, bw, acc[0][g]);
          acc[1][g] = mfma_bf16(a1, bw, acc[1][g]);
        }
      }
    }
#pragma unroll
    for (int m = 0; m < 2; ++m)
#pragma unroll
      for (int g = 0; g < 3; ++g)
        red[(w * 6 + m * 3 + g) * 64 + l] = acc[m][g];
    __syncthreads();
    if (w < 2) {
      int m = w;
      f32x4 as_[3];
#pragma unroll
      for (int g = 0; g < 3; ++g) as_[g] = (f32x4){0.f, 0.f, 0.f, 0.f};
#pragma unroll
      for (int ww = 0; ww < 8; ++ww)
#pragma unroll
        for (int g = 0; g < 3; ++g)
          as_[g] = as_[g] + red[(ww * 6 + m * 3 + g) * 64 + l];
#pragma unroll
      for (int r = 0; r < 4; ++r) {
        int b = m * 16 + q * 4 + r;
        float ghr = bhr + as_[0][r], ghz = bhz + as_[1][r], ghn = bhn + as_[2][r];
        float rg = 1.f / (1.f + expf(-(gi0[r] + ghr)));
        float zg = 1.f / (1.f + expf(-(gi1[r] + ghz)));
        float ng = tanhf(gi2[r] + rg * ghn);
        float hn = (1.f - zg) * ng + zg * hold[r];
        hold[r] = hn;
        unsigned short hb = f2bf(hn);
        wb[b * 1024 + j] = hb;
        esb[((size_t)b * Ss + s) * 1024 + j] = hb;
        if (s == Ss - 1) h[b * 1024 + j] = hn;
      }
    }
    gbar(bar, NBE, bc);
  }
}

// ---------------- persistent decoder ----------------
// 256 blocks x 256 thr (cooperative, 1 blk/CU). Roles:
//   blk 0-63:   gh GEMM  (Whd rows {g*1024 + blk*16 + 0..15} in LDS, 96KB)
//   blk 64-127: gi GEMM + gates (Wic slice in LDS, 96KB)
//   blk 128-255: attention (b=(blk-128)>>2, 2 s-slices) + hc-fold
// all blocks: ctxsm phase (jt=blk&7, b=blk>>3 — exact k_ctxsm body).
// Per step: A{att+hc+gh} bar B{softmax+ctx} bar C{gi+gates} bar. Init folded.
__global__ __launch_bounds__(256) void k_dec_pers(
    const unsigned short* __restrict__ Whd, const unsigned short* __restrict__ Wic,
    const unsigned short* __restrict__ esq, const unsigned short* __restrict__ av,
    const float* __restrict__ dgixt, const int* __restrict__ tgt,
    const float* __restrict__ bh, float* __restrict__ h,
    unsigned short* __restrict__ hbf, float* __restrict__ ctx,
    unsigned short* __restrict__ ctxbf, float* __restrict__ attL,
    float* __restrict__ ghbuf, unsigned short* __restrict__ hcbf,
    int* __restrict__ bar) {
  __shared__ unsigned short Ws[48 * 1024];  // 96KB weight slice (gh/gi blocks)
  __shared__ f32x4 red[4 * 6 * 64];         // 24KB split-K exchange
  __shared__ float hs[1024];                // 4KB h (att) / scratch
  __shared__ float wS[512];                 // ctxsm softmax weights
  __shared__ float wm[4], wsm[4];
  __shared__ float red2[128];
  int tid = threadIdx.x;
  int blk = blockIdx.x;
  int wv = tid >> 6, l = tid & 63;
  int fr = l & 15, q = l >> 4;
  int bc = 0;
  // ---- stage weight slice once ----
  int jsl = (blk & 63) * 16;
  if (blk < 128) {
    const uint4* src = (const uint4*)((blk < 64) ? Whd : Wic);
    uint4* dst = (uint4*)Ws;
#pragma unroll
    for (int it = 0; it < 24; ++it) {
      int idx = it * 256 + tid;           // 0..6143
      int lr = idx >> 7, c = idx & 127;
      int grow = (lr >> 4) * 1024 + jsl + (lr & 15);
      dst[lr * 128 + (c ^ (lr & 7))] = src[(size_t)grow * 128 + c];
    }
  }
  const bf16x8* Wsv = (const bf16x8*)Ws;
  int jw = jsl + fr;  // gemm-role column
  float bhr = bh[jw], bhz = bh[1024 + jw], bhn = bh[2048 + jw];
  // ---- init: ctx = enc final h (blocks 0-127 cover 32x1024) ----
  if (blk < 128) {
    int idx = blk * 256 + tid;
    float v = h[idx];
    ctx[idx] = v;
    ctxbf[idx] = f2bf(v);
  }
  gbar(bar, NBD, bc);
  // ---- init: h0 = gru(0, [start_emb, ctx0]) : gi blocks, hzero+usestart ----
  if (blk >= 64 && blk < 128) {
    f32x4 acc[2][3];
#pragma unroll
    for (int m = 0; m < 2; ++m)
#pragma unroll
      for (int g = 0; g < 3; ++g) acc[m][g] = (f32x4){0.f, 0.f, 0.f, 0.f};
    int kb = wv * 256 + q * 8;
    const unsigned short* A0 = ctxbf + fr * 1024 + kb;
#pragma unroll
    for (int kt = 0; kt < 256; kt += 32) {
      bf16x8 a0 = *(const bf16x8*)(A0 + kt);
      bf16x8 a1 = *(const bf16x8*)(A0 + 16 * 1024 + kt);
      int c8 = (kb + kt) >> 3;
#pragma unroll
      for (int g = 0; g < 3; ++g) {
        bf16x8 bw = Wsv[(g * 16 + fr) * 128 + (c8 ^ (fr & 7))];
        acc[0][g] = mfma_bf16(a0, bw, acc[0][g]);
        acc[1][g] = mfma_bf16(a1, bw, acc[1][g]);
      }
    }
#pragma unroll
    for (int m = 0; m < 2; ++m)
#pragma unroll
      for (int g = 0; g < 3; ++g)
        red[(wv * 6 + m * 3 + g) * 64 + l] = acc[m][g];
    __syncthreads();
    if (wv < 2) {
      int m = wv;
      f32x4 as_[3];
#pragma unroll
      for (int g = 0; g < 3; ++g) as_[g] = (f32x4){0.f, 0.f, 0.f, 0.f};
#pragma unroll
      for (int ww = 0; ww < 4; ++ww)
#pragma unroll
        for (int g = 0; g < 3; ++g)
          as_[g] = as_[g] + red[(ww * 6 + m * 3 + g) * 64 + l];
#pragma unroll
      for (int r = 0; r < 4; ++r) {
        int b = m * 16 + q * 4 + r;
        const float* gp = dgixt + (size_t)1 * H3 + jw;  // usestart: char 1
        float gir = gp[0] + as_[0][r];
        float giz = gp[1024] + as_[1][r];
        float gin = gp[2048] + as_[2][r];
        float rg = 1.f / (1.f + expf(-(gir + bhr)));
        float zg = 1.f / (1.f + expf(-(giz + bhz)));
        float ng = tanhf(gin + rg * bhn);
        float hn = (1.f - zg) * ng;  // hold = 0
        h[b * 1024 + jw] = hn;
        hbf[b * 1024 + jw] = f2bf(hn);
      }
    }
  }
  gbar(bar, NBD, bc);
  // ---- main loop ----
  for (int t = 0; t < Tt; ++t) {
    // ===== phase A: attention + hc-fold (blk>=128) | gh GEMM (blk<64) =====
    if (blk >= 128) {
      int ab = (blk - 128) >> 2, aq = (blk - 128) & 3;
      for (int i = tid; i < 1024; i += 256) hs[i] = h[ab * 1024 + i];
      __syncthreads();
      {  // hc fold: j = aq*256+tid
        int j2 = aq * 256 + tid;
        hcbf[(size_t)t * (Bb * Hh) + ab * 1024 + j2] = f2bf(hs[j2] + ctx[ab * 1024 + j2]);
      }
      int sg = tid >> 2, li = tid & 3;
      int s0 = aq * 128 + sg;  // and s0+64
      const unsigned short* ep0 = esq + (size_t)(ab * 512 + s0) * 1024;
      const unsigned short* ep1 = ep0 + 64 * 1024;
      float acc0 = 0.f, acc1 = 0.f;
#pragma unroll 4
      for (int i = 0; i < 32; ++i) {
        int k = (i * 4 + li) * 8;
        uint4 e0 = *(const uint4*)(ep0 + k);
        uint4 e1 = *(const uint4*)(ep1 + k);
        float4 h0 = *(const float4*)&hs[k];
        float4 h1 = *(const float4*)&hs[k + 4];
        acc0 += lof(e0.x) * h0.x + hif(e0.x) * h0.y + lof(e0.y) * h0.z + hif(e0.y) * h0.w +
                lof(e0.z) * h1.x + hif(e0.z) * h1.y + lof(e0.w) * h1.z + hif(e0.w) * h1.w;
        acc1 += lof(e1.x) * h0.x + hif(e1.x) * h0.y + lof(e1.y) * h0.z + hif(e1.y) * h0.w +
                lof(e1.z) * h1.x + hif(e1.z) * h1.y + lof(e1.w) * h1.z + hif(e1.w) * h1.w;
      }
      acc0 += __shfl_xor(acc0, 1);
      acc0 += __shfl_xor(acc0, 2);
      acc1 += __shfl_xor(acc1, 1);
      acc1 += __shfl_xor(acc1, 2);
      if (li == 0) {
        attL[ab * 512 + s0] = acc0;
        attL[ab * 512 + s0 + 64] = acc1;
      }
    } else if (blk < 64) {
      // gh = hbf @ Whd[rows]^T -> ghbuf raw (bias added in gates)
      f32x4 acc[2][3];
#pragma unroll
      for (int m = 0; m < 2; ++m)
#pragma unroll
        for (int g = 0; g < 3; ++g) acc[m][g] = (f32x4){0.f, 0.f, 0.f, 0.f};
      int kb = wv * 256 + q * 8;
      const unsigned short* A0 = hbf + fr * 1024 + kb;
#pragma unroll
      for (int kt = 0; kt < 256; kt += 32) {
        bf16x8 a0 = *(const bf16x8*)(A0 + kt);
        bf16x8 a1 = *(const bf16x8*)(A0 + 16 * 1024 + kt);
        int c8 = (kb + kt) >> 3;
#pragma unroll
        for (int g = 0; g < 3; ++g) {
          bf16x8 bw = Wsv[(g * 16 + fr) * 128 + (c8 ^ (fr & 7))];
          acc[0][g] = mfma_bf16(a0, bw, acc[0][g]);
          acc[1][g] = mfma_bf16(a1, bw, acc[1][g]);
        }
      }
#pragma unroll
      for (int m = 0; m < 2; ++m)
#pragma unroll
        for (int g = 0; g < 3; ++g)
          red[(wv * 6 + m * 3 + g) * 64 + l] = acc[m][g];
      __syncthreads();
      if (wv < 2) {
        int m = wv;
        f32x4 as_[3];
#pragma unroll
        for (int g = 0; g < 3; ++g) as_[g] = (f32x4){0.f, 0.f, 0.f, 0.f};
#pragma unroll
        for (int ww = 0; ww < 4; ++ww)
#pragma unroll
          for (int g = 0; g < 3; ++g)
            as_[g] = as_[g] + red[(ww * 6 + m * 3 + g) * 64 + l];
#pragma unroll
        for (int r = 0; r < 4; ++r) {
          int b = m * 16 + q * 4 + r;
#pragma unroll
          for (int g = 0; g < 3; ++g)
            ghbuf[b * H3 + g * 1024 + jw] = as_[g][r];
        }
      }
    }
    if (t == Tt - 1) break;  // last step: only hc (+unused att) needed
    gbar(bar, NBD, bc);
    // ===== phase B: softmax + ctx = w @ av (all blocks; exact k_ctxsm) =====
    {
      int b2 = blk >> 3, jt = blk & 7;
      float a0 = attL[b2 * Ss + tid * 2];
      float a1 = attL[b2 * Ss + tid * 2 + 1];
      float m = fmaxf(a0, a1);
      for (int d = 1; d < 64; d <<= 1) m = fmaxf(m, __shfl_xor(m, d));
      if ((tid & 63) == 0) wm[tid >> 6] = m;
      __syncthreads();
      m = fmaxf(fmaxf(wm[0], wm[1]), fmaxf(wm[2], wm[3]));
      float e0 = expf(a0 - m), e1 = expf(a1 - m);
      wS[tid * 2] = e0;
      wS[tid * 2 + 1] = e1;
      float ssum = e0 + e1;
      for (int d = 1; d < 64; d <<= 1) ssum += __shfl_xor(ssum, d);
      if ((tid & 63) == 0) wsm[tid >> 6] = ssum;
      __syncthreads();
      float scale = 1.f / (wsm[0] + wsm[1] + wsm[2] + wsm[3]);
      int j = jt * 128 + (tid & 127);
      int sh = tid >> 7;
      const unsigned short* avp = av + (size_t)(b2 * Ss + sh * 256) * Hh + j;
      float acc = 0.f;
#pragma unroll 16
      for (int s = 0; s < 256; ++s) acc += wS[sh * 256 + s] * bf2f(avp[(size_t)s * Hh]);
      if (sh == 1) red2[tid & 127] = acc;
      __syncthreads();
      if (sh == 0) {
        float v = (acc + red2[tid & 127]) * scale;
        ctx[b2 * Hh + j] = v;
        ctxbf[b2 * Hh + j] = f2bf(v);
      }
    }
    gbar(bar, NBD, bc);
    // ===== phase C: gi GEMM + gates (blk 64-127) =====
    if (blk >= 64 && blk < 128) {
      f32x4 acc[2][3];
#pragma unroll
      for (int m = 0; m < 2; ++m)
#pragma unroll
        for (int g = 0; g < 3; ++g) acc[m][g] = (f32x4){0.f, 0.f, 0.f, 0.f};
      int kb = wv * 256 + q * 8;
      const unsigned short* A0 = ctxbf + fr * 1024 + kb;
#pragma unroll
      for (int kt = 0; kt < 256; kt += 32) {
        bf16x8 a0 = *(const bf16x8*)(A0 + kt);
        bf16x8 a1 = *(const bf16x8*)(A0 + 16 * 1024 + kt);
        int c8 = (kb + kt) >> 3;
#pragma unroll
        for (int g = 0; g < 3; ++g) {
          bf16x8 bw = Wsv[(g * 16 + fr) * 128 + (c8 ^ (fr & 7))];
          acc[0][g] = mfma_bf16(a0, bw, acc[0][g]);
          acc[1][g] = mfma_bf16(a1, bw, acc[1][g]);
        }
      }
#pragma unroll
      for (int m = 0; m < 2; ++m)
#pragma unroll
        for (int g = 0; g < 3; ++g)
          red[(wv * 6 + m * 3 + g) * 64 + l] = acc[m][g];
      __syncthreads();
      if (wv < 2) {
        int m = wv;
        f32x4 as_[3];
#pragma unroll
        for (int g = 0; g < 3; ++g) as_[g] = (f32x4){0.f, 0.f, 0.f, 0.f};
#pragma unroll
        for (int ww = 0; ww < 4; ++ww)
#pragma unroll
          for (int g = 0; g < 3; ++g)
            as_[g] = as_[g] + red[(ww * 6 + m * 3 + g) * 64 + l];
#pragma unroll
        for (int r = 0; r < 4; ++r) {
          int b = m * 16 + q * 4 + r;
          int c = tgt[b * Tt + t];
          const float* gp = dgixt + (size_t)c * H3 + jw;
          float gir = gp[0] + as_[0][r];
          float giz = gp[1024] + as_[1][r];
          float gin = gp[2048] + as_[2][r];
          const float* g2 = ghbuf + b * H3 + jw;
          float ghr = bhr + g2[0];
          float ghz = bhz + g2[1024];
          float ghn = bhn + g2[2048];
          float rg = 1.f / (1.f + expf(-(gir + ghr)));
          float zg = 1.f / (1.f + expf(-(giz + ghz)));
          float ng = tanhf(gin + rg * ghn);
          float hn = (1.f - zg) * ng + zg * h[b * 1024 + jw];
          h[b * 1024 + jw] = hn;
          hbf[b * 1024 + jw] = f2bf(hn);
        }
      }
    }
    gbar(bar, NBD, bc);
  }
}

// ---------------- host ----------------
extern "C" void kernel_launch(void* const* d_in, const int* in_sizes, int n_in,
                              void* d_out, int out_size, void* d_ws, size_t ws_size,
                              hipStream_t stream) {
  (void)in_sizes; (void)n_in; (void)out_size; (void)ws_size;
  const int*   src_chars = (const int*)d_in[0];
  const int*   src_langs = (const int*)d_in[1];
  const int*   tgt_chars = (const int*)d_in[2];
  const float* char_emb  = (const float*)d_in[3];
  const float* lang_emb  = (const float*)d_in[4];
  const float* fc_W  = (const float*)d_in[5];
  const float* fc_b  = (const float*)d_in[6];
  const float* enc_Wi = (const float*)d_in[7];
  const float* enc_Wh = (const float*)d_in[8];
  const float* enc_bi = (const float*)d_in[9];
  const float* enc_bh = (const float*)d_in[10];
  const float* dec_Wi = (const float*)d_in[11];
  const float* dec_Wh = (const float*)d_in[12];
  const float* dec_bi = (const float*)d_in[13];
  const float* dec_bh = (const float*)d_in[14];
  const float* Wq  = (const float*)d_in[15];
  const float* Wk  = (const float*)d_in[16];
  const float* Wcs = (const float*)d_in[17];
  const float* W1 = (const float*)d_in[18];
  const float* b1 = (const float*)d_in[19];
  const float* W2 = (const float*)d_in[20];
  const float* b2 = (const float*)d_in[21];
  const float* W3 = (const float*)d_in[22];
  float* out = (float*)d_out;

  char* ws = (char*)d_ws;
  unsigned short* esbf  = (unsigned short*)(ws + O_ESBF);
  unsigned short* esq   = (unsigned short*)(ws + O_ESQ);
  unsigned short* avbf  = (unsigned short*)(ws + O_AVBF);
  unsigned short* hcbf  = (unsigned short*)(ws + O_HCBF);
  unsigned short* WheB  = (unsigned short*)(ws + O_WHE);
  unsigned short* WhdB  = (unsigned short*)(ws + O_WHD);
  unsigned short* WicB  = (unsigned short*)(ws + O_WIC);
  unsigned short* WkB   = (unsigned short*)(ws + O_WKB);
  unsigned short* WqTB  = (unsigned short*)(ws + O_WQT);
  unsigned short* W1B   = (unsigned short*)(ws + O_W1B);
  unsigned short* W2B   = (unsigned short*)(ws + O_W2B);
  unsigned short* W3B   = (unsigned short*)(ws + O_W3B);
  float* xcat   = (float*)(ws + O_XCAT);
  float* embfc  = (float*)(ws + O_EMBFC);
  float* gitab  = (float*)(ws + O_GITAB);
  float* avtab  = (float*)(ws + O_AVTAB);
  float* dgixt  = (float*)(ws + O_DGIXT);
  float* ghbuf  = (float*)(ws + O_GH);
  float* h      = (float*)(ws + O_H);
  unsigned short* hbf   = (unsigned short*)(ws + O_HBF);
  float* ctx    = (float*)(ws + O_CTX);
  unsigned short* ctxbf = (unsigned short*)(ws + O_CTXBF);
  float* attL   = (float*)(ws + O_ATTL);
  unsigned short* G1 = esq;   // alias: dead after decoder
  unsigned short* G2 = avbf;  // alias: dead after decoder
  int* cltab = (int*)(ws + O_GI);                               // 64KB
  unsigned short* hbf2 = (unsigned short*)(ws + O_GI + 65536);  // 64KB enc dbuf
  int* bar = (int*)(ws + O_GI + 131072);   // [0]=enc counter, [32]=dec counter

  dim3 blk(256);

  // ---- tables (fp32) ----
  k_xcat<<<640, blk, 0, stream>>>(char_emb, lang_emb, xcat);
  k_cltab<<<64, blk, 0, stream>>>(src_chars, src_langs, cltab, bar);
  k_gemm<true><<<dim3(4, 5), blk, 0, stream>>>(xcat, 1024, fc_W, 1024, fc_b, embfc, 512, 1024);
  k_gemm<true><<<dim3(24, 5), blk, 0, stream>>>(embfc, 512, enc_Wi, 512, enc_bi, gitab, H3, 512);
  k_gemm<false><<<dim3(8, 5), blk, 0, stream>>>(embfc, 512, Wcs, 512, nullptr, avtab, Hh, 512);
  k_gemm<true><<<dim3(24, 1), blk, 0, stream>>>(embfc + 512 * 512, 512, dec_Wi, 1536, dec_bi,
                                                dgixt, H3, 512);
  // ---- weight conversions ----
  k_cvt<<<1536, blk, 0, stream>>>(enc_Wh, 1024, 10, WheB);
  k_cvt<<<1536, blk, 0, stream>>>(dec_Wh, 1024, 10, WhdB);
  k_cvt<<<1536, blk, 0, stream>>>(dec_Wi + 512, 1536, 10, WicB);
  k_cvt<<<512,  blk, 0, stream>>>(Wk, 1024, 10, WkB);
  k_cvt<<<2048, blk, 0, stream>>>(W1, 1024, 10, W1B);
  k_cvt<<<4096, blk, 0, stream>>>(W2, 4096, 12, W2B);
  k_cvt<<<128,  blk, 0, stream>>>(W3, 2048, 11, W3B);
  k_transcvt<<<dim3(32, 32), dim3(32, 8), 0, stream>>>(Wq, WqTB);

  // ---- encoder scan: persistent cooperative kernel ----
  {
    const unsigned short* p_whe = WheB;
    const float* p_git = gitab;
    const int* p_cl = cltab;
    const float* p_bh = enc_bh;
    float* p_h = h;
    unsigned short* p_h0 = hbf;
    unsigned short* p_h1 = hbf2;
    unsigned short* p_esb = esbf;
    int* p_bar = bar;
    void* kargs[] = {(void*)&p_whe, (void*)&p_git, (void*)&p_cl, (void*)&p_bh,
                     (void*)&p_h, (void*)&p_h0, (void*)&p_h1, (void*)&p_esb,
                     (void*)&p_bar};
    hipLaunchCooperativeKernel((const void*)k_enc_pers, dim3(NBE), dim3(512), kargs, 0, stream);
  }

  // ---- esq = es @ Wq (for att = esq.h); av = es @ Wk^T + avtab ----
  k_bgemm<0, false, false><<<dim3(8, 128), blk, 0, stream>>>(
      esbf, 1024, WqTB, 1024, nullptr, esq, 1024, 1024, nullptr, nullptr, nullptr);
  k_bgemm<1, false, false><<<dim3(8, 128), blk, 0, stream>>>(
      esbf, 1024, WkB, 1024, nullptr, avbf, 1024, 1024, avtab, src_langs, src_chars);

  // ---- decoder: persistent cooperative kernel (init + 128 steps) ----
  {
    const unsigned short* p_whd = WhdB;
    const unsigned short* p_wic = WicB;
    const unsigned short* p_esq = esq;
    const unsigned short* p_av = avbf;
    const float* p_dgixt = dgixt;
    const int* p_tgt = tgt_chars;
    const float* p_bh = dec_bh;
    float* p_h = h;
    unsigned short* p_hbf = hbf;
    float* p_ctx = ctx;
    unsigned short* p_ctxbf = ctxbf;
    float* p_attL = attL;
    float* p_gh = ghbuf;
    unsigned short* p_hc = hcbf;
    int* p_bar = bar + 32;
    void* kargs[] = {(void*)&p_whd, (void*)&p_wic, (void*)&p_esq, (void*)&p_av,
                     (void*)&p_dgixt, (void*)&p_tgt, (void*)&p_bh, (void*)&p_h,
                     (void*)&p_hbf, (void*)&p_ctx, (void*)&p_ctxbf, (void*)&p_attL,
                     (void*)&p_gh, (void*)&p_hc, (void*)&p_bar};
    hipLaunchCooperativeKernel((const void*)k_dec_pers, dim3(NBD), dim3(256), kargs, 0, stream);
  }

  // ---- MLP: scores = relu(relu(hc@W1^T+b1)@W2^T+b2)@W3^T ----
  k_bgemm<0, true, true><<<dim3(32, 32), blk, 0, stream>>>(
      hcbf, 1024, W1B, 1024, b1, G1, 4096, 1024, nullptr, nullptr, nullptr);
  k_bgemm<0, true, true><<<dim3(16, 32), blk, 0, stream>>>(
      G1, 4096, W2B, 4096, b2, G2, 2048, 4096, nullptr, nullptr, nullptr);
  k_bgemm<2, false, false><<<dim3(1, 32), blk, 0, stream>>>(
      G2, 2048, W3B, 2048, nullptr, out, 0, 2048, nullptr, nullptr, nullptr);
}

// Round 8
// 9208.447 us; speedup vs baseline: 1.4576x; 1.4576x over previous
//
#include <hip/hip_runtime.h>
#include <math.h>

// GRU enc-dec w/ attention. B=32,S=512,T=128,V=128,L=5,E=512,H=1024,F=2048.
// R10: R9 resubmit with the phase-B divergent __syncthreads removed (UB, hang
//     suspect). Persistent decoder per R8 counters (67us/step, HBM 6.8%, all
//     pipes idle): (1) 128 blk x 512 thr -> 8 waves/CU; (2) tree barrier
//     (4x32+root) vs 256 flat atomics; (3) phase-B w@av loads 2B -> 16B/lane.
//     Softmax/attention order bit-identical; ctx sum regrouped (fp32).
//     Encoder (R7, proven, 8790us total) untouched.

#define Bb 32
#define Ss 512
#define Tt 128
#define Vv 128
#define Hh 1024
#define H3 3072
#define APAD 40
#define NBE 64    // persistent encoder blocks
#define NBD 128   // persistent decoder blocks

typedef __attribute__((ext_vector_type(8))) short bf16x8;
typedef __attribute__((ext_vector_type(4))) float f32x4;

__device__ inline f32x4 mfma_bf16(bf16x8 a, bf16x8 b, f32x4 c) {
  return __builtin_amdgcn_mfma_f32_16x16x32_bf16(a, b, c, 0, 0, 0);
}
__device__ inline unsigned short f2bf(float f) {
  unsigned u = __builtin_bit_cast(unsigned, f);
  unsigned r = (u + 0x7fffu + ((u >> 16) & 1u)) >> 16;
  return (unsigned short)r;
}
__device__ inline float lof(unsigned u) { return __builtin_bit_cast(float, u << 16); }
__device__ inline float hif(unsigned u) { return __builtin_bit_cast(float, u & 0xffff0000u); }
__device__ inline float bf2f(unsigned short h) {
  return __builtin_bit_cast(float, ((unsigned)h) << 16);
}

// ---------------- workspace offsets (BYTES) ----------------
#define O_ESBF   0UL            // es bf16      [B*S][1024]  32MB
#define O_ESQ    33554432UL     // esq bf16     [B*S][1024]  32MB  (aliased: G1 in MLP)
#define O_AVBF   67108864UL     // av bf16      [B*S][1024]  32MB  (aliased: G2 in MLP)
#define O_HCBF   100663296UL    // hc bf16      [T*B][1024]   8MB
#define O_WHE    109051904UL    // enc_Wh bf16  [3072][1024]  6MB
#define O_WHD    115343360UL    // dec_Wh bf16  6MB
#define O_WIC    121634816UL    // dec_Wi ctx-cols bf16 [3072][1024] 6MB
#define O_WKB    127926272UL    // Wk bf16 [1024][1024] 2MB
#define O_WQT    130023424UL    // Wq^T bf16 [1024][1024] 2MB
#define O_W1B    132120576UL    // W1 bf16 [4096][1024] 8MB
#define O_W2B    140509184UL    // W2 bf16 [2048][4096] 16MB
#define O_W3B    157286400UL    // W3 bf16 [128][2048] 0.5MB
#define O_XCAT   157810688UL    // fp32 [640][1024]
#define O_EMBFC  160432128UL    // fp32 [640][512]
#define O_GITAB  161742848UL    // fp32 [640][3072]
#define O_AVTAB  169607168UL    // fp32 [640][1024]
#define O_DGIXT  172228608UL    // fp32 [128][3072]
#define O_GH     173801472UL    // fp32 [32][3072]
#define O_GI     174194688UL    // 384KB: cltab(64KB) + hbf2(64KB) + bars(1KB)
#define O_H      174587904UL    // fp32 [32][1024]
#define O_HBF    174718976UL    // bf16 [32][1024]
#define O_CTX    174784512UL    // fp32 [32][1024]
#define O_CTXBF  174915584UL    // bf16 [32][1024]
#define O_ATTL   174981120UL    // fp32 [32][512]
// total ~167MB

// ---------------- setup helpers ----------------
__global__ void k_xcat(const float* __restrict__ ce, const float* __restrict__ le,
                       float* __restrict__ xcat) {
  int row = blockIdx.x;  // l*128 + c
  int l = row >> 7, c = row & 127;
  int i = threadIdx.x * 4;
  float4 v;
  if (i < 512) v = *(const float4*)(ce + c * 512 + i);
  else         v = *(const float4*)(le + l * 512 + (i - 512));
  *(float4*)(xcat + (size_t)row * 1024 + i) = v;
}

__global__ void k_cltab(const int* __restrict__ sc, const int* __restrict__ sl,
                        int* __restrict__ cl, int* __restrict__ bar) {
  if (blockIdx.x == 0 && threadIdx.x < 256) bar[threadIdx.x] = 0;  // all counters
  int i = blockIdx.x * 256 + threadIdx.x;  // 16384 = 32b * 512s
  int b = i >> 9, s = i & 511;
  cl[s * 32 + b] = sl[b * Ss + s] * 128 + sc[b * Ss + s];
}

__global__ void k_cvt(const float* __restrict__ src, int ld, int lc,
                      unsigned short* __restrict__ dst) {
  size_t i = ((size_t)blockIdx.x * 256 + threadIdx.x) * 8;
  size_t r = i >> lc;
  int c = (int)(i & ((1u << lc) - 1));
  const float* s = src + r * (size_t)ld + c;
  float4 v0 = *(const float4*)s;
  float4 v1 = *(const float4*)(s + 4);
  union { unsigned short us[8]; uint4 u; } o;
  o.us[0] = f2bf(v0.x); o.us[1] = f2bf(v0.y); o.us[2] = f2bf(v0.z); o.us[3] = f2bf(v0.w);
  o.us[4] = f2bf(v1.x); o.us[5] = f2bf(v1.y); o.us[6] = f2bf(v1.z); o.us[7] = f2bf(v1.w);
  *(uint4*)(dst + i) = o.u;
}

__global__ void k_transcvt(const float* __restrict__ in, unsigned short* __restrict__ out) {
  __shared__ float t[32][33];
  int c0 = blockIdx.x * 32, r0 = blockIdx.y * 32;
  int tx = threadIdx.x, ty = threadIdx.y;
  for (int i = ty; i < 32; i += 8)
    t[i][tx] = in[(size_t)(r0 + i) * 1024 + c0 + tx];
  __syncthreads();
  for (int i = ty; i < 32; i += 8)
    out[(size_t)(c0 + i) * 1024 + r0 + tx] = f2bf(t[tx][i]);
}

// ---------------- fp32 tiled GEMM (setup tables only): C=A@W^T ----------------
template <bool BIAS>
__global__ __launch_bounds__(256) void k_gemm(
    const float* __restrict__ A, int lda, const float* __restrict__ W, int ldw,
    const float* __restrict__ bias, float* __restrict__ C, int ldc, int K) {
  __shared__ float As[8][128];
  __shared__ float Ws[8][128];
  int tid = threadIdx.x;
  int n0 = blockIdx.x * 128, m0 = blockIdx.y * 128;
  int tx = tid & 15, ty = tid >> 4;
  int lrow = tid >> 1, lseg = (tid & 1) * 4;
  const float* Ap = A + (size_t)(m0 + lrow) * lda + lseg;
  const float* Wp = W + (size_t)(n0 + lrow) * ldw + lseg;
  float acc[8][8];
#pragma unroll
  for (int i = 0; i < 8; ++i)
#pragma unroll
    for (int j = 0; j < 8; ++j) acc[i][j] = 0.f;
  for (int kt = 0; kt < K; kt += 8) {
    float4 av = *(const float4*)(Ap + kt);
    float4 wv = *(const float4*)(Wp + kt);
    __syncthreads();
    As[lseg + 0][lrow] = av.x; As[lseg + 1][lrow] = av.y;
    As[lseg + 2][lrow] = av.z; As[lseg + 3][lrow] = av.w;
    Ws[lseg + 0][lrow] = wv.x; Ws[lseg + 1][lrow] = wv.y;
    Ws[lseg + 2][lrow] = wv.z; Ws[lseg + 3][lrow] = wv.w;
    __syncthreads();
#pragma unroll
    for (int kk = 0; kk < 8; ++kk) {
      float a[8], b[8];
      *(float4*)(a + 0) = *(const float4*)(&As[kk][ty * 8 + 0]);
      *(float4*)(a + 4) = *(const float4*)(&As[kk][ty * 8 + 4]);
      *(float4*)(b + 0) = *(const float4*)(&Ws[kk][tx * 8 + 0]);
      *(float4*)(b + 4) = *(const float4*)(&Ws[kk][tx * 8 + 4]);
#pragma unroll
      for (int i = 0; i < 8; ++i)
#pragma unroll
        for (int j = 0; j < 8; ++j) acc[i][j] = fmaf(a[i], b[j], acc[i][j]);
    }
  }
#pragma unroll
  for (int i = 0; i < 8; ++i) {
    int r = m0 + ty * 8 + i;
#pragma unroll
    for (int j = 0; j < 8; ++j) {
      int c = n0 + tx * 8 + j;
      float v = acc[i][j];
      if (BIAS) v += bias[c];
      C[(size_t)r * ldc + c] = v;
    }
  }
}

// ---------------- bf16 MFMA GEMM: C[M,N] = A[M,K] @ W[N,K]^T ----------------
// EPI: 0 store bf16; 1 +=avtab[lang*128+char][col], store bf16; 2 fp32 scatter to out
template <int EPI, bool RELU, bool BIAS>
__global__ __launch_bounds__(256) void k_bgemm(
    const unsigned short* __restrict__ A, int lda,
    const unsigned short* __restrict__ W, int ldw,
    const float* __restrict__ bias, void* __restrict__ Cout, int ldc, int K,
    const float* __restrict__ avtab, const int* __restrict__ gl,
    const int* __restrict__ gc) {
  __shared__ unsigned short As[128 * APAD];
  __shared__ unsigned short Bs[128 * APAD];
  int tid = threadIdx.x;
  int n0 = blockIdx.x * 128, m0 = blockIdx.y * 128;
  int w = tid >> 6, l = tid & 63;
  int mw = (w & 1) * 64, nw = (w >> 1) * 64;
  int lrow = tid >> 1, lk = (tid & 1) * 16;
  const unsigned short* Ap = A + (size_t)(m0 + lrow) * lda + lk;
  const unsigned short* Wp = W + (size_t)(n0 + lrow) * ldw + lk;
  int fr = l & 15, fk = (l >> 4) * 8;
  f32x4 acc[4][4];
#pragma unroll
  for (int i = 0; i < 4; ++i)
#pragma unroll
    for (int j = 0; j < 4; ++j) acc[i][j] = (f32x4){0.f, 0.f, 0.f, 0.f};
  for (int kt = 0; kt < K; kt += 32) {
    uint4 a0 = *(const uint4*)(Ap + kt);
    uint4 a1 = *(const uint4*)(Ap + kt + 8);
    uint4 b0 = *(const uint4*)(Wp + kt);
    uint4 b1 = *(const uint4*)(Wp + kt + 8);
    __syncthreads();
    *(uint4*)&As[lrow * APAD + lk] = a0;
    *(uint4*)&As[lrow * APAD + lk + 8] = a1;
    *(uint4*)&Bs[lrow * APAD + lk] = b0;
    *(uint4*)&Bs[lrow * APAD + lk + 8] = b1;
    __syncthreads();
    bf16x8 af[4], bfg[4];
#pragma unroll
    for (int i = 0; i < 4; ++i) af[i] = *(const bf16x8*)&As[(mw + i * 16 + fr) * APAD + fk];
#pragma unroll
    for (int j = 0; j < 4; ++j) bfg[j] = *(const bf16x8*)&Bs[(nw + j * 16 + fr) * APAD + fk];
#pragma unroll
    for (int i = 0; i < 4; ++i)
#pragma unroll
      for (int j = 0; j < 4; ++j) acc[i][j] = mfma_bf16(af[i], bfg[j], acc[i][j]);
  }
#pragma unroll
  for (int i = 0; i < 4; ++i)
#pragma unroll
    for (int j = 0; j < 4; ++j) {
      int col = n0 + nw + j * 16 + fr;
#pragma unroll
      for (int r = 0; r < 4; ++r) {
        int row = m0 + mw + i * 16 + (l >> 4) * 4 + r;
        float v = acc[i][j][r];
        if (BIAS) v += bias[col];
        if (RELU) v = fmaxf(v, 0.f);
        if (EPI == 0) {
          ((unsigned short*)Cout)[(size_t)row * ldc + col] = f2bf(v);
        } else if (EPI == 1) {
          int cl = gl[row] * 128 + gc[row];
          ((unsigned short*)Cout)[(size_t)row * ldc + col] =
              f2bf(v + avtab[(size_t)cl * 1024 + col]);
        } else {
          int tt = row >> 5, bb = row & 31;
          ((float*)Cout)[(size_t)bb * (Tt * Vv) + tt * Vv + col] = v;
        }
      }
    }
}

// ---------------- persistent encoder scan (R7, proven) ----------------
__global__ __launch_bounds__(512) void k_enc_pers(
    const unsigned short* __restrict__ Whe, const float* __restrict__ gitab,
    const int* __restrict__ cltab, const float* __restrict__ bh,
    float* __restrict__ h, unsigned short* __restrict__ hbf0,
    unsigned short* __restrict__ hbf1, unsigned short* __restrict__ esb,
    int* __restrict__ bar) {
  __shared__ unsigned short Ws[48 * 1024];  // 96KB
  __shared__ f32x4 red[8 * 6 * 64];         // 48KB
  int tid = threadIdx.x;
  int blk = blockIdx.x;
  int w = tid >> 6, l = tid & 63;
  int fr = l & 15, q = l >> 4;
  int j = blk * 16 + fr;
  {  // stage 48 Wh rows, XOR-swizzled per 16B chunk
    uint4* dst = (uint4*)Ws;
    const uint4* src = (const uint4*)Whe;
#pragma unroll
    for (int it = 0; it < 12; ++it) {
      int idx = it * 512 + tid;           // 0..6143
      int lr = idx >> 7, c = idx & 127;   // local row, chunk
      int grow = (lr >> 4) * 1024 + blk * 16 + (lr & 15);
      dst[lr * 128 + (c ^ (lr & 7))] = src[(size_t)grow * 128 + c];
    }
  }
  float bhr = bh[j], bhz = bh[1024 + j], bhn = bh[2048 + j];
  float hold[4] = {0.f, 0.f, 0.f, 0.f};
  __syncthreads();
  const bf16x8* Wsv = (const bf16x8*)Ws;
  int bc = 0;
  for (int s = 0; s < Ss; ++s) {
    unsigned short* wb = (s & 1) ? hbf1 : hbf0;
    const unsigned short* rb = (s & 1) ? hbf0 : hbf1;
    float gi0[4], gi1[4], gi2[4];
    if (w < 2) {
#pragma unroll
      for (int r = 0; r < 4; ++r) {
        int b = w * 16 + q * 4 + r;
        int c = cltab[s * 32 + b];
        const float* gp = gitab + (size_t)c * H3 + j;
        gi0[r] = gp[0]; gi1[r] = gp[1024]; gi2[r] = gp[2048];
      }
    }
    f32x4 acc[2][3];
#pragma unroll
    for (int m = 0; m < 2; ++m)
#pragma unroll
      for (int g = 0; g < 3; ++g) acc[m][g] = (f32x4){0.f, 0.f, 0.f, 0.f};
    if (s > 0) {
      int kb = w * 128 + q * 8;
      const unsigned short* A0 = rb + fr * 1024 + kb;
#pragma unroll
      for (int kt = 0; kt < 128; kt += 32) {
        bf16x8 a0 = *(const bf16x8*)(A0 + kt);
        bf16x8 a1 = *(const bf16x8*)(A0 + 16 * 1024 + kt);
        int c8 = (kb + kt) >> 3;
#pragma unroll
        for (int g = 0; g < 3; ++g) {
          bf16x8 bw = Wsv[(g * 16 + fr) * 128 + (c8 ^ (fr & 7))];
          acc[0][g] = mfma_bf16(a0, bw, acc[0][g]);
          acc[1][g] = mfma_bf16(a1, bw, acc[1][g]);
        }
      }
    }
#pragma unroll
    for (int m = 0; m < 2; ++m)
#pragma unroll
      for (int g = 0; g < 3; ++g)
        red[(w * 6 + m * 3 + g) * 64 + l] = acc[m][g];
    __syncthreads();
    if (w < 2) {
      int m = w;
      f32x4 as_[3];
#pragma unroll
      for (int g = 0; g < 3; ++g) as_[g] = (f32x4){0.f, 0.f, 0.f, 0.f};
#pragma unroll
      for (int ww = 0; ww < 8; ++ww)
#pragma unroll
        for (int g = 0; g < 3; ++g)
          as_[g] = as_[g] + red[(ww * 6 + m * 3 + g) * 64 + l];
#pragma unroll
      for (int r = 0; r < 4; ++r) {
        int b = m * 16 + q * 4 + r;
        float ghr = bhr + as_[0][r], ghz = bhz + as_[1][r], ghn = bhn + as_[2][r];
        float rg = 1.f / (1.f + expf(-(gi0[r] + ghr)));
        float zg = 1.f / (1.f + expf(-(gi1[r] + ghz)));
        float ng = tanhf(gi2[r] + rg * ghn);
        float hn = (1.f - zg) * ng + zg * hold[r];
        hold[r] = hn;
        unsigned short hb = f2bf(hn);
        wb[b * 1024 + j] = hb;
        esb[((size_t)b * Ss + s) * 1024 + j] = hb;
        if (s == Ss - 1) h[b * 1024 + j] = hn;
      }
    }
    __syncthreads();
    if (tid == 0) {
      __hip_atomic_fetch_add(bar, 1, __ATOMIC_RELEASE, __HIP_MEMORY_SCOPE_AGENT);
      ++bc;
      int tgt = NBE * bc;
      while (__hip_atomic_load(bar, __ATOMIC_RELAXED, __HIP_MEMORY_SCOPE_AGENT) < tgt)
        __builtin_amdgcn_s_sleep(1);
      __builtin_amdgcn_fence(__ATOMIC_ACQUIRE, "agent");
    }
    __syncthreads();
  }
}

// ---------------- persistent decoder (R10) ----------------
// 128 blocks x 512 thr (8 waves/CU). Tree barrier: 4 group lines (32 blocks
// each, cacheline-spaced) + root; ~36 serialized atomics vs 256 flat.
// blk 0-63:  Whd slice in LDS. A: gh GEMM (8-wave split-K, encoder order).
// blk 64-127: Wic slice in LDS. A: attention (batch=(blk-64)>>1, half) +
//            hc-fold. C: gi GEMM + gates.
// all:       B: softmax (exact k_ctxsm order; uniform barriers) + vectorized
//            w@av (lane owns 8 j-cols bf16x8; si owns s=si mod 16; fixed-order
//            fp32 LDS reduce — ctx sum regrouped vs k_ctxsm).
__global__ __launch_bounds__(512) void k_dec_pers(
    const unsigned short* __restrict__ Whd, const unsigned short* __restrict__ Wic,
    const unsigned short* __restrict__ esq, const unsigned short* __restrict__ av,
    const float* __restrict__ dgixt, const int* __restrict__ tgt,
    const float* __restrict__ bh, float* __restrict__ h,
    unsigned short* __restrict__ hbf, float* __restrict__ ctx,
    unsigned short* __restrict__ ctxbf, float* __restrict__ attL,
    float* __restrict__ ghbuf, unsigned short* __restrict__ hcbf,
    int* __restrict__ bar) {
  __shared__ unsigned short Ws[48 * 1024];  // 96KB weight slice
  __shared__ float scr[12 * 1024];          // 48KB: red (gemm) / partials (B)
  __shared__ float hs[1024];                // 4KB h stage (att)
  __shared__ float wS[512];
  __shared__ float wm[4], wsm[4];
  f32x4* red = (f32x4*)scr;
  int tid = threadIdx.x;
  int blk = blockIdx.x;
  int wv = tid >> 6, l = tid & 63;
  int fr = l & 15, q = l >> 4;
  int rnd = 0;
  bool isGH = blk < 64;
  // ---- stage weight slice once (gh: Whd, gi: Wic), XOR-swizzled ----
  int jsl = (blk & 63) * 16;
  {
    const uint4* src = (const uint4*)(isGH ? Whd : Wic);
    uint4* dst = (uint4*)Ws;
#pragma unroll
    for (int it = 0; it < 12; ++it) {
      int idx = it * 512 + tid;           // 0..6143
      int lr = idx >> 7, c = idx & 127;
      int grow = (lr >> 4) * 1024 + jsl + (lr & 15);
      dst[lr * 128 + (c ^ (lr & 7))] = src[(size_t)grow * 128 + c];
    }
  }
  const bf16x8* Wsv = (const bf16x8*)Ws;
  int jw = jsl + fr;
  float bhr = bh[jw], bhz = bh[1024 + jw], bhn = bh[2048 + jw];
  int batch = (blk - 64) >> 1, hf = (blk - 64) & 1;  // att-role mapping
  int b2 = blk >> 2, jq = blk & 3;                   // ctxsm-role mapping

#define GBAR()                                                                          \
  do {                                                                                  \
    __syncthreads();                                                                    \
    if (tid == 0) {                                                                     \
      ++rnd;                                                                            \
      int gl_ = (blk >> 5) * 16;                                                        \
      int old_ = __hip_atomic_fetch_add(&bar[gl_], 1, __ATOMIC_RELEASE,                 \
                                        __HIP_MEMORY_SCOPE_AGENT);                      \
      if (old_ == rnd * 32 - 1)                                                         \
        __hip_atomic_fetch_add(&bar[64], 1, __ATOMIC_RELEASE,                           \
                               __HIP_MEMORY_SCOPE_AGENT);                               \
      while (__hip_atomic_load(&bar[64], __ATOMIC_RELAXED,                              \
                               __HIP_MEMORY_SCOPE_AGENT) < rnd * 4)                     \
        __builtin_amdgcn_s_sleep(1);                                                    \
      __builtin_amdgcn_fence(__ATOMIC_ACQUIRE, "agent");                                \
    }                                                                                   \
    __syncthreads();                                                                    \
  } while (0)

  // ---- init: ctx = enc final h ----
  if (tid < 256) {
    int idx = blk * 256 + tid;
    float v = h[idx];
    ctx[idx] = v;
    ctxbf[idx] = f2bf(v);
  }
  GBAR();
  // ---- init: h0 = gru(0, [start_emb, ctx0]) (gi blocks; hzero, char=1) ----
  if (!isGH) {
    f32x4 acc[2][3];
#pragma unroll
    for (int m = 0; m < 2; ++m)
#pragma unroll
      for (int g = 0; g < 3; ++g) acc[m][g] = (f32x4){0.f, 0.f, 0.f, 0.f};
    int kb = wv * 128 + q * 8;
    const unsigned short* A0 = ctxbf + fr * 1024 + kb;
#pragma unroll
    for (int kt = 0; kt < 128; kt += 32) {
      bf16x8 a0 = *(const bf16x8*)(A0 + kt);
      bf16x8 a1 = *(const bf16x8*)(A0 + 16 * 1024 + kt);
      int c8 = (kb + kt) >> 3;
#pragma unroll
      for (int g = 0; g < 3; ++g) {
        bf16x8 bw = Wsv[(g * 16 + fr) * 128 + (c8 ^ (fr & 7))];
        acc[0][g] = mfma_bf16(a0, bw, acc[0][g]);
        acc[1][g] = mfma_bf16(a1, bw, acc[1][g]);
      }
    }
#pragma unroll
    for (int m = 0; m < 2; ++m)
#pragma unroll
      for (int g = 0; g < 3; ++g)
        red[(wv * 6 + m * 3 + g) * 64 + l] = acc[m][g];
    __syncthreads();
    if (wv < 2) {
      int m = wv;
      f32x4 as_[3];
#pragma unroll
      for (int g = 0; g < 3; ++g) as_[g] = (f32x4){0.f, 0.f, 0.f, 0.f};
#pragma unroll
      for (int ww = 0; ww < 8; ++ww)
#pragma unroll
        for (int g = 0; g < 3; ++g)
          as_[g] = as_[g] + red[(ww * 6 + m * 3 + g) * 64 + l];
      const float* gp = dgixt + (size_t)1 * H3 + jw;  // start char = 1
#pragma unroll
      for (int r = 0; r < 4; ++r) {
        int b = m * 16 + q * 4 + r;
        float gir = gp[0] + as_[0][r];
        float giz = gp[1024] + as_[1][r];
        float gin = gp[2048] + as_[2][r];
        float rg = 1.f / (1.f + expf(-(gir + bhr)));
        float zg = 1.f / (1.f + expf(-(giz + bhz)));
        float ng = tanhf(gin + rg * bhn);
        float hn = (1.f - zg) * ng;  // hold = 0
        h[b * 1024 + jw] = hn;
        hbf[b * 1024 + jw] = f2bf(hn);
      }
    }
  }
  GBAR();
  // ---- main loop ----
  for (int t = 0; t < Tt; ++t) {
    // ===== phase A: gh GEMM (blk<64) | attention + hc-fold (blk>=64) =====
    if (isGH) {
      f32x4 acc[2][3];
#pragma unroll
      for (int m = 0; m < 2; ++m)
#pragma unroll
        for (int g = 0; g < 3; ++g) acc[m][g] = (f32x4){0.f, 0.f, 0.f, 0.f};
      int kb = wv * 128 + q * 8;
      const unsigned short* A0 = hbf + fr * 1024 + kb;
#pragma unroll
      for (int kt = 0; kt < 128; kt += 32) {
        bf16x8 a0 = *(const bf16x8*)(A0 + kt);
        bf16x8 a1 = *(const bf16x8*)(A0 + 16 * 1024 + kt);
        int c8 = (kb + kt) >> 3;
#pragma unroll
        for (int g = 0; g < 3; ++g) {
          bf16x8 bw = Wsv[(g * 16 + fr) * 128 + (c8 ^ (fr & 7))];
          acc[0][g] = mfma_bf16(a0, bw, acc[0][g]);
          acc[1][g] = mfma_bf16(a1, bw, acc[1][g]);
        }
      }
#pragma unroll
      for (int m = 0; m < 2; ++m)
#pragma unroll
        for (int g = 0; g < 3; ++g)
          red[(wv * 6 + m * 3 + g) * 64 + l] = acc[m][g];
      __syncthreads();
      if (wv < 2) {
        int m = wv;
        f32x4 as_[3];
#pragma unroll
        for (int g = 0; g < 3; ++g) as_[g] = (f32x4){0.f, 0.f, 0.f, 0.f};
#pragma unroll
        for (int ww = 0; ww < 8; ++ww)
#pragma unroll
          for (int g = 0; g < 3; ++g)
            as_[g] = as_[g] + red[(ww * 6 + m * 3 + g) * 64 + l];
#pragma unroll
        for (int r = 0; r < 4; ++r) {
          int b = m * 16 + q * 4 + r;
#pragma unroll
          for (int g = 0; g < 3; ++g)
            ghbuf[b * H3 + g * 1024 + jw] = as_[g][r];
        }
      }
    } else {
      for (int i = tid; i < 1024; i += 512) hs[i] = h[batch * 1024 + i];
      __syncthreads();
      {  // hc fold: this block covers j = hf*512 .. hf*512+511
        int j2 = hf * 512 + tid;
        hcbf[(size_t)t * (Bb * Hh) + batch * 1024 + j2] =
            f2bf(hs[j2] + ctx[batch * 1024 + j2]);
      }
      int sg = tid >> 2, li = tid & 3;
      int s0 = hf * 256 + sg;  // and s0+128
      const unsigned short* ep0 = esq + (size_t)(batch * 512 + s0) * 1024;
      const unsigned short* ep1 = ep0 + 128 * 1024;
      float acc0 = 0.f, acc1 = 0.f;
#pragma unroll 4
      for (int i = 0; i < 32; ++i) {
        int k = (i * 4 + li) * 8;
        uint4 e0 = *(const uint4*)(ep0 + k);
        uint4 e1 = *(const uint4*)(ep1 + k);
        float4 h0 = *(const float4*)&hs[k];
        float4 h1 = *(const float4*)&hs[k + 4];
        acc0 += lof(e0.x) * h0.x + hif(e0.x) * h0.y + lof(e0.y) * h0.z + hif(e0.y) * h0.w +
                lof(e0.z) * h1.x + hif(e0.z) * h1.y + lof(e0.w) * h1.z + hif(e0.w) * h1.w;
        acc1 += lof(e1.x) * h0.x + hif(e1.x) * h0.y + lof(e1.y) * h0.z + hif(e1.y) * h0.w +
                lof(e1.z) * h1.x + hif(e1.z) * h1.y + lof(e1.w) * h1.z + hif(e1.w) * h1.w;
      }
      acc0 += __shfl_xor(acc0, 1);
      acc0 += __shfl_xor(acc0, 2);
      acc1 += __shfl_xor(acc1, 1);
      acc1 += __shfl_xor(acc1, 2);
      if (li == 0) {
        attL[batch * 512 + s0] = acc0;
        attL[batch * 512 + s0 + 128] = acc1;
      }
    }
    if (t == Tt - 1) break;
    GBAR();
    // ===== phase B: softmax (uniform barriers) + vectorized ctx =====
    {
      float a0 = 0.f, a1 = 0.f;
      if (tid < 256) {
        a0 = attL[b2 * Ss + tid * 2];
        a1 = attL[b2 * Ss + tid * 2 + 1];
        float m = fmaxf(a0, a1);
        for (int d = 1; d < 64; d <<= 1) m = fmaxf(m, __shfl_xor(m, d));
        if ((tid & 63) == 0) wm[tid >> 6] = m;
      }
      __syncthreads();
      if (tid < 256) {
        float m = fmaxf(fmaxf(wm[0], wm[1]), fmaxf(wm[2], wm[3]));
        float e0 = expf(a0 - m), e1 = expf(a1 - m);
        wS[tid * 2] = e0;
        wS[tid * 2 + 1] = e1;
        float ssum = e0 + e1;
        for (int d = 1; d < 64; d <<= 1) ssum += __shfl_xor(ssum, d);
        if ((tid & 63) == 0) wsm[tid >> 6] = ssum;
      }
      __syncthreads();
      float scale = 1.f / (wsm[0] + wsm[1] + wsm[2] + wsm[3]);
      int g = tid & 31, si = tid >> 5;
      const unsigned short* avp = av + (size_t)(b2 * 512) * 1024 + jq * 256 + g * 8;
      float a8[8] = {0.f, 0.f, 0.f, 0.f, 0.f, 0.f, 0.f, 0.f};
#pragma unroll 4
      for (int s = si; s < 512; s += 16) {
        float wv2 = wS[s];
        uint4 e = *(const uint4*)(avp + (size_t)s * 1024);
        a8[0] += wv2 * lof(e.x); a8[1] += wv2 * hif(e.x);
        a8[2] += wv2 * lof(e.y); a8[3] += wv2 * hif(e.y);
        a8[4] += wv2 * lof(e.z); a8[5] += wv2 * hif(e.z);
        a8[6] += wv2 * lof(e.w); a8[7] += wv2 * hif(e.w);
      }
      __syncthreads();  // red/scr free (phase A done for this block)
#pragma unroll
      for (int k2 = 0; k2 < 8; ++k2) scr[tid * 8 + k2] = a8[k2];
      __syncthreads();
      if (tid < 256) {
        float p = 0.f;
#pragma unroll
        for (int si2 = 0; si2 < 16; ++si2) p += scr[si2 * 256 + tid];
        float v = p * scale;
        int j3 = b2 * 1024 + jq * 256 + tid;
        ctx[j3] = v;
        ctxbf[j3] = f2bf(v);
      }
    }
    GBAR();
    // ===== phase C: gi GEMM + gates (blk 64-127) =====
    if (!isGH) {
      f32x4 acc[2][3];
#pragma unroll
      for (int m = 0; m < 2; ++m)
#pragma unroll
        for (int g = 0; g < 3; ++g) acc[m][g] = (f32x4){0.f, 0.f, 0.f, 0.f};
      int kb = wv * 128 + q * 8;
      const unsigned short* A0 = ctxbf + fr * 1024 + kb;
#pragma unroll
      for (int kt = 0; kt < 128; kt += 32) {
        bf16x8 a0 = *(const bf16x8*)(A0 + kt);
        bf16x8 a1 = *(const bf16x8*)(A0 + 16 * 1024 + kt);
        int c8 = (kb + kt) >> 3;
#pragma unroll
        for (int g = 0; g < 3; ++g) {
          bf16x8 bw = Wsv[(g * 16 + fr) * 128 + (c8 ^ (fr & 7))];
          acc[0][g] = mfma_bf16(a0, bw, acc[0][g]);
          acc[1][g] = mfma_bf16(a1, bw, acc[1][g]);
        }
      }
#pragma unroll
      for (int m = 0; m < 2; ++m)
#pragma unroll
        for (int g = 0; g < 3; ++g)
          red[(wv * 6 + m * 3 + g) * 64 + l] = acc[m][g];
      __syncthreads();
      if (wv < 2) {
        int m = wv;
        f32x4 as_[3];
#pragma unroll
        for (int g = 0; g < 3; ++g) as_[g] = (f32x4){0.f, 0.f, 0.f, 0.f};
#pragma unroll
        for (int ww = 0; ww < 8; ++ww)
#pragma unroll
          for (int g = 0; g < 3; ++g)
            as_[g] = as_[g] + red[(ww * 6 + m * 3 + g) * 64 + l];
#pragma unroll
        for (int r = 0; r < 4; ++r) {
          int b = m * 16 + q * 4 + r;
          int c = tgt[b * Tt + t];
          const float* gp = dgixt + (size_t)c * H3 + jw;
          float gir = gp[0] + as_[0][r];
          float giz = gp[1024] + as_[1][r];
          float gin = gp[2048] + as_[2][r];
          const float* g2 = ghbuf + b * H3 + jw;
          float ghr = bhr + g2[0];
          float ghz = bhz + g2[1024];
          float ghn = bhn + g2[2048];
          float rg = 1.f / (1.f + expf(-(gir + ghr)));
          float zg = 1.f / (1.f + expf(-(giz + ghz)));
          float ng = tanhf(gin + rg * ghn);
          float hn = (1.f - zg) * ng + zg * h[b * 1024 + jw];
          h[b * 1024 + jw] = hn;
          hbf[b * 1024 + jw] = f2bf(hn);
        }
      }
    }
    GBAR();
  }
#undef GBAR
}

// ---------------- host ----------------
extern "C" void kernel_launch(void* const* d_in, const int* in_sizes, int n_in,
                              void* d_out, int out_size, void* d_ws, size_t ws_size,
                              hipStream_t stream) {
  (void)in_sizes; (void)n_in; (void)out_size; (void)ws_size;
  const int*   src_chars = (const int*)d_in[0];
  const int*   src_langs = (const int*)d_in[1];
  const int*   tgt_chars = (const int*)d_in[2];
  const float* char_emb  = (const float*)d_in[3];
  const float* lang_emb  = (const float*)d_in[4];
  const float* fc_W  = (const float*)d_in[5];
  const float* fc_b  = (const float*)d_in[6];
  const float* enc_Wi = (const float*)d_in[7];
  const float* enc_Wh = (const float*)d_in[8];
  const float* enc_bi = (const float*)d_in[9];
  const float* enc_bh = (const float*)d_in[10];
  const float* dec_Wi = (const float*)d_in[11];
  const float* dec_Wh = (const float*)d_in[12];
  const float* dec_bi = (const float*)d_in[13];
  const float* dec_bh = (const float*)d_in[14];
  const float* Wq  = (const float*)d_in[15];
  const float* Wk  = (const float*)d_in[16];
  const float* Wcs = (const float*)d_in[17];
  const float* W1 = (const float*)d_in[18];
  const float* b1 = (const float*)d_in[19];
  const float* W2 = (const float*)d_in[20];
  const float* b2 = (const float*)d_in[21];
  const float* W3 = (const float*)d_in[22];
  float* out = (float*)d_out;

  char* ws = (char*)d_ws;
  unsigned short* esbf  = (unsigned short*)(ws + O_ESBF);
  unsigned short* esq   = (unsigned short*)(ws + O_ESQ);
  unsigned short* avbf  = (unsigned short*)(ws + O_AVBF);
  unsigned short* hcbf  = (unsigned short*)(ws + O_HCBF);
  unsigned short* WheB  = (unsigned short*)(ws + O_WHE);
  unsigned short* WhdB  = (unsigned short*)(ws + O_WHD);
  unsigned short* WicB  = (unsigned short*)(ws + O_WIC);
  unsigned short* WkB   = (unsigned short*)(ws + O_WKB);
  unsigned short* WqTB  = (unsigned short*)(ws + O_WQT);
  unsigned short* W1B   = (unsigned short*)(ws + O_W1B);
  unsigned short* W2B   = (unsigned short*)(ws + O_W2B);
  unsigned short* W3B   = (unsigned short*)(ws + O_W3B);
  float* xcat   = (float*)(ws + O_XCAT);
  float* embfc  = (float*)(ws + O_EMBFC);
  float* gitab  = (float*)(ws + O_GITAB);
  float* avtab  = (float*)(ws + O_AVTAB);
  float* dgixt  = (float*)(ws + O_DGIXT);
  float* ghbuf  = (float*)(ws + O_GH);
  float* h      = (float*)(ws + O_H);
  unsigned short* hbf   = (unsigned short*)(ws + O_HBF);
  float* ctx    = (float*)(ws + O_CTX);
  unsigned short* ctxbf = (unsigned short*)(ws + O_CTXBF);
  float* attL   = (float*)(ws + O_ATTL);
  unsigned short* G1 = esq;   // alias: dead after decoder
  unsigned short* G2 = avbf;  // alias: dead after decoder
  int* cltab = (int*)(ws + O_GI);                               // 64KB
  unsigned short* hbf2 = (unsigned short*)(ws + O_GI + 65536);  // 64KB enc dbuf
  int* bar = (int*)(ws + O_GI + 131072);  // [0..64] dec tree, [128] enc

  dim3 blk(256);

  // ---- tables (fp32) ----
  k_xcat<<<640, blk, 0, stream>>>(char_emb, lang_emb, xcat);
  k_cltab<<<64, blk, 0, stream>>>(src_chars, src_langs, cltab, bar);
  k_gemm<true><<<dim3(4, 5), blk, 0, stream>>>(xcat, 1024, fc_W, 1024, fc_b, embfc, 512, 1024);
  k_gemm<true><<<dim3(24, 5), blk, 0, stream>>>(embfc, 512, enc_Wi, 512, enc_bi, gitab, H3, 512);
  k_gemm<false><<<dim3(8, 5), blk, 0, stream>>>(embfc, 512, Wcs, 512, nullptr, avtab, Hh, 512);
  k_gemm<true><<<dim3(24, 1), blk, 0, stream>>>(embfc + 512 * 512, 512, dec_Wi, 1536, dec_bi,
                                                dgixt, H3, 512);
  // ---- weight conversions ----
  k_cvt<<<1536, blk, 0, stream>>>(enc_Wh, 1024, 10, WheB);
  k_cvt<<<1536, blk, 0, stream>>>(dec_Wh, 1024, 10, WhdB);
  k_cvt<<<1536, blk, 0, stream>>>(dec_Wi + 512, 1536, 10, WicB);
  k_cvt<<<512,  blk, 0, stream>>>(Wk, 1024, 10, WkB);
  k_cvt<<<2048, blk, 0, stream>>>(W1, 1024, 10, W1B);
  k_cvt<<<4096, blk, 0, stream>>>(W2, 4096, 12, W2B);
  k_cvt<<<128,  blk, 0, stream>>>(W3, 2048, 11, W3B);
  k_transcvt<<<dim3(32, 32), dim3(32, 8), 0, stream>>>(Wq, WqTB);

  // ---- encoder scan: persistent cooperative kernel (R7) ----
  {
    const unsigned short* p_whe = WheB;
    const float* p_git = gitab;
    const int* p_cl = cltab;
    const float* p_bh = enc_bh;
    float* p_h = h;
    unsigned short* p_h0 = hbf;
    unsigned short* p_h1 = hbf2;
    unsigned short* p_esb = esbf;
    int* p_bar = bar + 128;
    void* kargs[] = {(void*)&p_whe, (void*)&p_git, (void*)&p_cl, (void*)&p_bh,
                     (void*)&p_h, (void*)&p_h0, (void*)&p_h1, (void*)&p_esb,
                     (void*)&p_bar};
    hipLaunchCooperativeKernel((const void*)k_enc_pers, dim3(NBE), dim3(512), kargs, 0, stream);
  }

  // ---- esq = es @ Wq (for att = esq.h); av = es @ Wk^T + avtab ----
  k_bgemm<0, false, false><<<dim3(8, 128), blk, 0, stream>>>(
      esbf, 1024, WqTB, 1024, nullptr, esq, 1024, 1024, nullptr, nullptr, nullptr);
  k_bgemm<1, false, false><<<dim3(8, 128), blk, 0, stream>>>(
      esbf, 1024, WkB, 1024, nullptr, avbf, 1024, 1024, avtab, src_langs, src_chars);

  // ---- decoder: persistent cooperative kernel (init + 128 steps) ----
  {
    const unsigned short* p_whd = WhdB;
    const unsigned short* p_wic = WicB;
    const unsigned short* p_esq = esq;
    const unsigned short* p_av = avbf;
    const float* p_dgixt = dgixt;
    const int* p_tgt = tgt_chars;
    const float* p_bh = dec_bh;
    float* p_h = h;
    unsigned short* p_hbf = hbf;
    float* p_ctx = ctx;
    unsigned short* p_ctxbf = ctxbf;
    float* p_attL = attL;
    float* p_gh = ghbuf;
    unsigned short* p_hc = hcbf;
    int* p_bar = bar;
    void* kargs[] = {(void*)&p_whd, (void*)&p_wic, (void*)&p_esq, (void*)&p_av,
                     (void*)&p_dgixt, (void*)&p_tgt, (void*)&p_bh, (void*)&p_h,
                     (void*)&p_hbf, (void*)&p_ctx, (void*)&p_ctxbf, (void*)&p_attL,
                     (void*)&p_gh, (void*)&p_hc, (void*)&p_bar};
    hipLaunchCooperativeKernel((const void*)k_dec_pers, dim3(NBD), dim3(512), kargs, 0, stream);
  }

  // ---- MLP: scores = relu(relu(hc@W1^T+b1)@W2^T+b2)@W3^T ----
  k_bgemm<0, true, true><<<dim3(32, 32), blk, 0, stream>>>(
      hcbf, 1024, W1B, 1024, b1, G1, 4096, 1024, nullptr, nullptr, nullptr);
  k_bgemm<0, true, true><<<dim3(16, 32), blk, 0, stream>>>(
      G1, 4096, W2B, 4096, b2, G2, 2048, 4096, nullptr, nullptr, nullptr);
  k_bgemm<2, false, false><<<dim3(1, 32), blk, 0, stream>>>(
      G2, 2048, W3B, 2048, nullptr, out, 0, 2048, nullptr, nullptr, nullptr);
}